// Round 13
// baseline (243.152 us; speedup 1.0000x reference)
//
#include <hip/hip_runtime.h>
#include <math.h>

// SE layer: x[32,256,64,64] f32, w1[16,256], w2[256,256]
// pooled = mean(x, HW); y = relu(pooled @ w1^T); outer = y⊗y (flat 256);
// s = sigmoid(outer @ w2^T); out = x * s[b,c]
//
// Cooperative-residency single-pass, inline global barrier, SMALL payload.
// R12 post-mortem: compiler targets 128 VGPRs (4 waves/EU) regardless of
// launch_bounds(,2); a 128-VGPR payload then spills (~23MB scratch, 159us).
// Fix: halve the payload. 1024 blocks x 256 thr (4 blocks/CU), SL=8 slices
// per block -> packed-bf16 payload r[8][8] = 64 VGPRs + ~50 working <= 128.
//  - x nt-loaded from HBM exactly once; pooled in f32 (exact); x retained
//    as packed bf16 in regs across the dependency (bf16 err ~0.0156 << 0.054).
//  - single inline global barrier (fetch_add + generation flag + s_sleep;
//    no opaque call -> nothing forces a spill). bar at d_ws+1MB (R11 bug fix).
//  - after barrier each block recomputes fc for its batch + its 8 channels.
// hipLaunchCooperativeKernel only for the co-residency guarantee; on any
// launch error -> R6 chunked fallback (67.6us).

#define B 32
#define C 256
#define HID 16
#define BD 256       // HID*HID
#define HW 4096      // 64*64
#define TPB 256
#define NBLK 1024
#define SL 8         // slices (b,c) per block; all in the same batch
#define CHUNKB 16    // fallback chunk size
#define AS __HIP_MEMORY_SCOPE_AGENT

typedef float vf4 __attribute__((ext_vector_type(4)));

__device__ __forceinline__ unsigned int bf16_rne(float f) {
    unsigned int u = __builtin_bit_cast(unsigned int, f);
    u += 0x7FFFu + ((u >> 16) & 1u);
    return u >> 16;
}
__device__ __forceinline__ float bf16_lo(unsigned int p) {
    return __builtin_bit_cast(float, p << 16);
}
__device__ __forceinline__ float bf16_hi(unsigned int p) {
    return __builtin_bit_cast(float, p & 0xFFFF0000u);
}

// zero barrier state (ws is 0xAA-poisoned); bar[0]=count, bar[1]=generation
__global__ __launch_bounds__(64) void init_kernel(unsigned int* __restrict__ bar) {
    if (threadIdx.x < 2) bar[threadIdx.x] = 0u;
}

__global__ __launch_bounds__(TPB, 4)
void se_onebar(const float* __restrict__ x, const float* __restrict__ w1,
               const float* __restrict__ w2, float* __restrict__ out,
               float* __restrict__ pooled, unsigned int* __restrict__ bar) {
    const int bid = blockIdx.x;
    const int t = threadIdx.x;
    const int bc0 = bid * SL;            // 8 consecutive slices, one batch
    const int b = bc0 >> 8;
    const int wv = t >> 6, ln = t & 63;

    __shared__ float red2[4][SL];
    __shared__ float pl[C];
    __shared__ float yv[HID];
    __shared__ float outer_s[BD];
    __shared__ float sv_sh[SL];

    unsigned int r[SL][8];               // 64 VGPRs: x as packed bf16

    // ---- phase 1: nt-load x once, pool in f32 (exact), pack bf16 ----
#pragma unroll
    for (int sl = 0; sl < SL; ++sl) {
        const vf4* xp = reinterpret_cast<const vf4*>(x + (size_t)(bc0 + sl) * HW);
        vf4 v0 = __builtin_nontemporal_load(&xp[t]);
        vf4 v1 = __builtin_nontemporal_load(&xp[t + 256]);
        vf4 v2 = __builtin_nontemporal_load(&xp[t + 512]);
        vf4 v3 = __builtin_nontemporal_load(&xp[t + 768]);
        float sum = ((v0.x + v0.y) + (v0.z + v0.w)) + ((v1.x + v1.y) + (v1.z + v1.w))
                  + ((v2.x + v2.y) + (v2.z + v2.w)) + ((v3.x + v3.y) + (v3.z + v3.w));
#pragma unroll
        for (int off = 32; off > 0; off >>= 1) sum += __shfl_down(sum, off, 64);
        if (ln == 0) red2[wv][sl] = sum;
        r[sl][0] = bf16_rne(v0.x) | (bf16_rne(v0.y) << 16);
        r[sl][1] = bf16_rne(v0.z) | (bf16_rne(v0.w) << 16);
        r[sl][2] = bf16_rne(v1.x) | (bf16_rne(v1.y) << 16);
        r[sl][3] = bf16_rne(v1.z) | (bf16_rne(v1.w) << 16);
        r[sl][4] = bf16_rne(v2.x) | (bf16_rne(v2.y) << 16);
        r[sl][5] = bf16_rne(v2.z) | (bf16_rne(v2.w) << 16);
        r[sl][6] = bf16_rne(v3.x) | (bf16_rne(v3.y) << 16);
        r[sl][7] = bf16_rne(v3.z) | (bf16_rne(v3.w) << 16);
    }
    __syncthreads();
    if (t < SL) {
        float mean = ((red2[0][t] + red2[1][t]) + (red2[2][t] + red2[3][t]))
                     * (1.0f / (float)HW);
        __hip_atomic_store(&pooled[bc0 + t], mean, __ATOMIC_RELAXED, AS);
    }

    // ---- inline global barrier (no call -> no spill) ----
    __syncthreads();
    if (t == 0) {
        unsigned int g = __hip_atomic_load(&bar[1], __ATOMIC_RELAXED, AS);
        unsigned int a = __hip_atomic_fetch_add(&bar[0], 1u, __ATOMIC_ACQ_REL, AS);
        if (a == (unsigned int)(NBLK - 1)) {
            __hip_atomic_store(&bar[0], 0u, __ATOMIC_RELAXED, AS);
            __hip_atomic_store(&bar[1], g + 1u, __ATOMIC_RELEASE, AS);
        } else {
            while (__hip_atomic_load(&bar[1], __ATOMIC_ACQUIRE, AS) == g)
                __builtin_amdgcn_s_sleep(1);
        }
    }
    __syncthreads();

    // ---- phase 2: fc chain for OWN batch + own 8 channels ----
    pl[t] = __hip_atomic_load(&pooled[b * C + t], __ATOMIC_RELAXED, AS);
    __syncthreads();
    {   // fc1 + relu: 16 hidden x 16 lanes, shfl_xor reduce
        const int h = t >> 4, j = t & 15;
        const float* w1r = w1 + h * C + j * 16;
        const float* plr = pl + j * 16;
        float p = 0.f;
#pragma unroll
        for (int k = 0; k < 16; ++k) p += plr[k] * w1r[k];
        p += __shfl_xor(p, 1, 64);
        p += __shfl_xor(p, 2, 64);
        p += __shfl_xor(p, 4, 64);
        p += __shfl_xor(p, 8, 64);
        if (j == 0) yv[h] = fmaxf(p, 0.f);
    }
    __syncthreads();
    outer_s[t] = yv[t >> 4] * yv[t & 15];
    __syncthreads();
    {   // fc2 + sigmoid for the block's 8 channels: 32 lanes per channel
        const int ci = t >> 5, j = t & 31;
        const int c = (bc0 & 255) + ci;
        const float* w2r  = w2 + (size_t)c * BD + j * 8;
        const float* orow = outer_s + j * 8;
        float p = 0.f;
#pragma unroll
        for (int k = 0; k < 8; ++k) p += orow[k] * w2r[k];
        p += __shfl_xor(p, 1, 64);
        p += __shfl_xor(p, 2, 64);
        p += __shfl_xor(p, 4, 64);
        p += __shfl_xor(p, 8, 64);
        p += __shfl_xor(p, 16, 64);
        if (j == 0) sv_sh[ci] = 1.0f / (1.0f + expf(-p));
    }
    __syncthreads();

    // ---- phase 3: unpack bf16 regs, scale, nt-store ----
#pragma unroll
    for (int sl = 0; sl < SL; ++sl) {
        const float sc = sv_sh[sl];
        vf4 o0, o1, o2, o3;
        o0.x = bf16_lo(r[sl][0]); o0.y = bf16_hi(r[sl][0]);
        o0.z = bf16_lo(r[sl][1]); o0.w = bf16_hi(r[sl][1]);
        o1.x = bf16_lo(r[sl][2]); o1.y = bf16_hi(r[sl][2]);
        o1.z = bf16_lo(r[sl][3]); o1.w = bf16_hi(r[sl][3]);
        o2.x = bf16_lo(r[sl][4]); o2.y = bf16_hi(r[sl][4]);
        o2.z = bf16_lo(r[sl][5]); o2.w = bf16_hi(r[sl][5]);
        o3.x = bf16_lo(r[sl][6]); o3.y = bf16_hi(r[sl][6]);
        o3.z = bf16_lo(r[sl][7]); o3.w = bf16_hi(r[sl][7]);
        o0 *= sc; o1 *= sc; o2 *= sc; o3 *= sc;
        vf4* op = reinterpret_cast<vf4*>(out + (size_t)(bc0 + sl) * HW);
        __builtin_nontemporal_store(o0, &op[t]);
        __builtin_nontemporal_store(o1, &op[t + 256]);
        __builtin_nontemporal_store(o2, &op[t + 512]);
        __builtin_nontemporal_store(o3, &op[t + 768]);
    }
}

// ================= fallback: round-6 chunked two-pass =================
__global__ __launch_bounds__(256) void pool_kernel(const float* __restrict__ x,
                                                   float* __restrict__ pooled,
                                                   int bc0) {
    const int bc = bc0 + blockIdx.x;
    const vf4* xp = reinterpret_cast<const vf4*>(x + (size_t)bc * HW);
    const int t = threadIdx.x;
    float sum = 0.f;
#pragma unroll
    for (int k = 0; k < 4; ++k) {
        vf4 v = xp[t + k * 256];
        sum += (v.x + v.y) + (v.z + v.w);
    }
#pragma unroll
    for (int off = 32; off > 0; off >>= 1) sum += __shfl_down(sum, off, 64);
    __shared__ float red[4];
    if ((t & 63) == 0) red[t >> 6] = sum;
    __syncthreads();
    if (t == 0)
        pooled[bc] = ((red[0] + red[1]) + (red[2] + red[3])) * (1.0f / (float)HW);
}

__global__ __launch_bounds__(256) void scale_kernel(const float* __restrict__ x,
                                                    const float* __restrict__ pooled,
                                                    const float* __restrict__ w1,
                                                    const float* __restrict__ w2,
                                                    float* __restrict__ out,
                                                    int bc0) {
    const int bc = bc0 + blockIdx.x;
    const int b = bc >> 8, c0 = bc & 255;
    const int t = threadIdx.x;

    const vf4* xp = reinterpret_cast<const vf4*>(x + (size_t)bc * HW);
    vf4 v0 = xp[t];
    vf4 v1 = xp[t + 256];
    vf4 v2 = xp[t + 512];
    vf4 v3 = xp[t + 768];

    __shared__ float pl[C];
    __shared__ float yv[HID];
    __shared__ float red[4];
    __shared__ float sc_sh;

    pl[t] = pooled[b * C + t];
    __syncthreads();
    {
        const int h = t >> 4, j = t & 15;
        const float* w1r = w1 + h * C + j * 16;
        const float* plr = pl + j * 16;
        float p = 0.f;
#pragma unroll
        for (int k = 0; k < 16; ++k) p += plr[k] * w1r[k];
        p += __shfl_xor(p, 1, 64);
        p += __shfl_xor(p, 2, 64);
        p += __shfl_xor(p, 4, 64);
        p += __shfl_xor(p, 8, 64);
        if (j == 0) yv[h] = fmaxf(p, 0.f);
    }
    __syncthreads();
    float term = yv[t >> 4] * yv[t & 15] * w2[(size_t)c0 * BD + t];
#pragma unroll
    for (int off = 32; off > 0; off >>= 1) term += __shfl_down(term, off, 64);
    if ((t & 63) == 0) red[t >> 6] = term;
    __syncthreads();
    if (t == 0)
        sc_sh = 1.0f / (1.0f + expf(-((red[0] + red[1]) + (red[2] + red[3]))));
    __syncthreads();
    const float sc = sc_sh;

    vf4* op = reinterpret_cast<vf4*>(out + (size_t)bc * HW);
    v0 *= sc; v1 *= sc; v2 *= sc; v3 *= sc;
    __builtin_nontemporal_store(v0, &op[t]);
    __builtin_nontemporal_store(v1, &op[t + 256]);
    __builtin_nontemporal_store(v2, &op[t + 512]);
    __builtin_nontemporal_store(v3, &op[t + 768]);
}

extern "C" void kernel_launch(void* const* d_in, const int* in_sizes, int n_in,
                              void* d_out, int out_size, void* d_ws, size_t ws_size,
                              hipStream_t stream) {
    const float* x  = (const float*)d_in[0];
    const float* w1 = (const float*)d_in[1];
    const float* w2 = (const float*)d_in[2];
    float* out = (float*)d_out;

    float* pooled = (float*)d_ws;                                  // 32 KB (8192 f)
    unsigned int* bar = (unsigned int*)((char*)d_ws + (1 << 20));  // at +1 MB

    init_kernel<<<1, 64, 0, stream>>>(bar);
    void* args[] = {(void*)&x, (void*)&w1, (void*)&w2, (void*)&out,
                    (void*)&pooled, (void*)&bar};
    hipError_t err = hipLaunchCooperativeKernel((const void*)se_onebar, dim3(NBLK),
                                                dim3(TPB), args, 0, stream);
    if (err != hipSuccess) {
        for (int cb = 0; cb < B; cb += CHUNKB) {
            const int bc0 = cb * C;
            pool_kernel<<<CHUNKB * C, 256, 0, stream>>>(x, pooled, bc0);
            scale_kernel<<<CHUNKB * C, 256, 0, stream>>>(x, pooled, w1, w2, out, bc0);
        }
    }
}

// Round 14
// 149.849 us; speedup vs baseline: 1.6226x; 1.6226x over previous
//
#include <hip/hip_runtime.h>
#include <math.h>

// SE layer: x[32,256,64,64] f32, w1[16,256], w2[256,256]
// pooled = mean(x, HW); y = relu(pooled @ w1^T); outer = y⊗y (flat 256);
// s = sigmoid(outer @ w2^T); out = x * s[b,c]
//
// Cooperative-residency single-pass, inline global barrier, NAMED-REGISTER
// payload. R12/R13 post-mortem: the r[SL][8] ARRAY is an alloca SROA can't
// promote (dynamic indices at SROA time) -> whole payload in scratch
// (R13: VGPR=64 = working set only, 43MB scratch traffic). Guide rule #20
// fix: NAMED variables. 32 named uint-vec4 vars = 128 VGPR payload,
// launch_bounds(256,2) -> 256 budget, ~170 total, no spill.
//  - x nt-loaded from HBM exactly once; pooled in f32 (exact); x retained
//    as packed bf16 in named regs (bf16 err ~0.0156 << 0.054 threshold).
//  - single inline global barrier (fetch_add + gen flag + s_sleep spin);
//    bar at d_ws+1MB (clear of pooled; R11 bug).
//  - after barrier each block recomputes fc for its batch + its 16 channels.
// hipLaunchCooperativeKernel only for co-residency (512 blocks = 2/CU);
// on any launch error -> R6 chunked fallback (67.6us).

#define B 32
#define C 256
#define HID 16
#define BD 256       // HID*HID
#define HW 4096      // 64*64
#define TPB 256
#define NBLK 512
#define SL 16        // slices (b,c) per block; all in the same batch
#define CHUNKB 16    // fallback chunk size
#define AS __HIP_MEMORY_SCOPE_AGENT

typedef float vf4 __attribute__((ext_vector_type(4)));
typedef unsigned int vu4 __attribute__((ext_vector_type(4)));

__device__ __forceinline__ unsigned int bf16_rne(float f) {
    unsigned int u = __builtin_bit_cast(unsigned int, f);
    u += 0x7FFFu + ((u >> 16) & 1u);
    return u >> 16;
}
__device__ __forceinline__ float bf16_lo(unsigned int p) {
    return __builtin_bit_cast(float, p << 16);
}
__device__ __forceinline__ float bf16_hi(unsigned int p) {
    return __builtin_bit_cast(float, p & 0xFFFF0000u);
}

// zero barrier state (ws is 0xAA-poisoned); bar[0]=count, bar[1]=generation
__global__ __launch_bounds__(64) void init_kernel(unsigned int* __restrict__ bar) {
    if (threadIdx.x < 2) bar[threadIdx.x] = 0u;
}

__global__ __launch_bounds__(TPB, 2)
void se_onebar(const float* __restrict__ x, const float* __restrict__ w1,
               const float* __restrict__ w2, float* __restrict__ out,
               float* __restrict__ pooled, unsigned int* __restrict__ bar) {
    const int bid = blockIdx.x;
    const int t = threadIdx.x;
    const int bc0 = bid * SL;            // 16 consecutive slices, one batch
    const int b = bc0 >> 8;
    const int wv = t >> 6, ln = t & 63;

    __shared__ float red2[4][SL];
    __shared__ float pl[C];
    __shared__ float yv[HID];
    __shared__ float outer_s[BD];
    __shared__ float sv_sh[SL];

    // ---- named payload: 32 x vu4 = 128 VGPRs of packed bf16 ----
#define DECLS(i) vu4 ra##i, rb##i;
    DECLS(0)  DECLS(1)  DECLS(2)  DECLS(3)
    DECLS(4)  DECLS(5)  DECLS(6)  DECLS(7)
    DECLS(8)  DECLS(9)  DECLS(10) DECLS(11)
    DECLS(12) DECLS(13) DECLS(14) DECLS(15)
#undef DECLS

    // ---- phase 1: nt-load x once, pool in f32 (exact), pack bf16 ----
#define PHASE1(i) { \
    const vf4* xp = reinterpret_cast<const vf4*>(x + (size_t)(bc0 + i) * HW); \
    vf4 v0 = __builtin_nontemporal_load(&xp[t]); \
    vf4 v1 = __builtin_nontemporal_load(&xp[t + 256]); \
    vf4 v2 = __builtin_nontemporal_load(&xp[t + 512]); \
    vf4 v3 = __builtin_nontemporal_load(&xp[t + 768]); \
    float sum = ((v0.x + v0.y) + (v0.z + v0.w)) + ((v1.x + v1.y) + (v1.z + v1.w)) \
              + ((v2.x + v2.y) + (v2.z + v2.w)) + ((v3.x + v3.y) + (v3.z + v3.w)); \
    sum += __shfl_down(sum, 32, 64); sum += __shfl_down(sum, 16, 64); \
    sum += __shfl_down(sum, 8, 64);  sum += __shfl_down(sum, 4, 64); \
    sum += __shfl_down(sum, 2, 64);  sum += __shfl_down(sum, 1, 64); \
    if (ln == 0) red2[wv][i] = sum; \
    ra##i.x = bf16_rne(v0.x) | (bf16_rne(v0.y) << 16); \
    ra##i.y = bf16_rne(v0.z) | (bf16_rne(v0.w) << 16); \
    ra##i.z = bf16_rne(v1.x) | (bf16_rne(v1.y) << 16); \
    ra##i.w = bf16_rne(v1.z) | (bf16_rne(v1.w) << 16); \
    rb##i.x = bf16_rne(v2.x) | (bf16_rne(v2.y) << 16); \
    rb##i.y = bf16_rne(v2.z) | (bf16_rne(v2.w) << 16); \
    rb##i.z = bf16_rne(v3.x) | (bf16_rne(v3.y) << 16); \
    rb##i.w = bf16_rne(v3.z) | (bf16_rne(v3.w) << 16); \
}
    PHASE1(0)  PHASE1(1)  PHASE1(2)  PHASE1(3)
    PHASE1(4)  PHASE1(5)  PHASE1(6)  PHASE1(7)
    PHASE1(8)  PHASE1(9)  PHASE1(10) PHASE1(11)
    PHASE1(12) PHASE1(13) PHASE1(14) PHASE1(15)
#undef PHASE1

    __syncthreads();
    if (t < SL) {
        float mean = ((red2[0][t] + red2[1][t]) + (red2[2][t] + red2[3][t]))
                     * (1.0f / (float)HW);
        __hip_atomic_store(&pooled[bc0 + t], mean, __ATOMIC_RELAXED, AS);
    }

    // ---- inline global barrier (no call -> no forced spill) ----
    __syncthreads();
    if (t == 0) {
        unsigned int g = __hip_atomic_load(&bar[1], __ATOMIC_RELAXED, AS);
        unsigned int a = __hip_atomic_fetch_add(&bar[0], 1u, __ATOMIC_ACQ_REL, AS);
        if (a == (unsigned int)(NBLK - 1)) {
            __hip_atomic_store(&bar[0], 0u, __ATOMIC_RELAXED, AS);
            __hip_atomic_store(&bar[1], g + 1u, __ATOMIC_RELEASE, AS);
        } else {
            while (__hip_atomic_load(&bar[1], __ATOMIC_ACQUIRE, AS) == g)
                __builtin_amdgcn_s_sleep(1);
        }
    }
    __syncthreads();

    // ---- phase 2: fc chain for OWN batch + own 16 channels ----
    pl[t] = __hip_atomic_load(&pooled[b * C + t], __ATOMIC_RELAXED, AS);
    __syncthreads();
    {   // fc1 + relu: 16 hidden x 16 lanes, shfl_xor reduce
        const int h = t >> 4, j = t & 15;
        const float* w1r = w1 + h * C + j * 16;
        const float* plr = pl + j * 16;
        float p = 0.f;
#pragma unroll
        for (int k = 0; k < 16; ++k) p += plr[k] * w1r[k];
        p += __shfl_xor(p, 1, 64);
        p += __shfl_xor(p, 2, 64);
        p += __shfl_xor(p, 4, 64);
        p += __shfl_xor(p, 8, 64);
        if (j == 0) yv[h] = fmaxf(p, 0.f);
    }
    __syncthreads();
    outer_s[t] = yv[t >> 4] * yv[t & 15];
    __syncthreads();
    {   // fc2 + sigmoid for the block's 16 channels: 16 lanes per channel
        const int ci = t >> 4, j = t & 15;
        const int c = (bc0 & 255) + ci;
        const float* w2r  = w2 + (size_t)c * BD + j * 16;
        const float* orow = outer_s + j * 16;
        float p = 0.f;
#pragma unroll
        for (int k = 0; k < 16; ++k) p += orow[k] * w2r[k];
        p += __shfl_xor(p, 1, 64);
        p += __shfl_xor(p, 2, 64);
        p += __shfl_xor(p, 4, 64);
        p += __shfl_xor(p, 8, 64);
        if (j == 0) sv_sh[ci] = 1.0f / (1.0f + expf(-p));
    }
    __syncthreads();

    // ---- phase 3: unpack named bf16 regs, scale, nt-store ----
#define PHASE3(i) { \
    const float sc = sv_sh[i]; \
    vf4 o0, o1, o2, o3; \
    o0.x = bf16_lo(ra##i.x); o0.y = bf16_hi(ra##i.x); \
    o0.z = bf16_lo(ra##i.y); o0.w = bf16_hi(ra##i.y); \
    o1.x = bf16_lo(ra##i.z); o1.y = bf16_hi(ra##i.z); \
    o1.z = bf16_lo(ra##i.w); o1.w = bf16_hi(ra##i.w); \
    o2.x = bf16_lo(rb##i.x); o2.y = bf16_hi(rb##i.x); \
    o2.z = bf16_lo(rb##i.y); o2.w = bf16_hi(rb##i.y); \
    o3.x = bf16_lo(rb##i.z); o3.y = bf16_hi(rb##i.z); \
    o3.z = bf16_lo(rb##i.w); o3.w = bf16_hi(rb##i.w); \
    o0 *= sc; o1 *= sc; o2 *= sc; o3 *= sc; \
    vf4* op = reinterpret_cast<vf4*>(out + (size_t)(bc0 + i) * HW); \
    __builtin_nontemporal_store(o0, &op[t]); \
    __builtin_nontemporal_store(o1, &op[t + 256]); \
    __builtin_nontemporal_store(o2, &op[t + 512]); \
    __builtin_nontemporal_store(o3, &op[t + 768]); \
}
    PHASE3(0)  PHASE3(1)  PHASE3(2)  PHASE3(3)
    PHASE3(4)  PHASE3(5)  PHASE3(6)  PHASE3(7)
    PHASE3(8)  PHASE3(9)  PHASE3(10) PHASE3(11)
    PHASE3(12) PHASE3(13) PHASE3(14) PHASE3(15)
#undef PHASE3
}

// ================= fallback: round-6 chunked two-pass =================
__global__ __launch_bounds__(256) void pool_kernel(const float* __restrict__ x,
                                                   float* __restrict__ pooled,
                                                   int bc0) {
    const int bc = bc0 + blockIdx.x;
    const vf4* xp = reinterpret_cast<const vf4*>(x + (size_t)bc * HW);
    const int t = threadIdx.x;
    float sum = 0.f;
#pragma unroll
    for (int k = 0; k < 4; ++k) {
        vf4 v = xp[t + k * 256];
        sum += (v.x + v.y) + (v.z + v.w);
    }
#pragma unroll
    for (int off = 32; off > 0; off >>= 1) sum += __shfl_down(sum, off, 64);
    __shared__ float red[4];
    if ((t & 63) == 0) red[t >> 6] = sum;
    __syncthreads();
    if (t == 0)
        pooled[bc] = ((red[0] + red[1]) + (red[2] + red[3])) * (1.0f / (float)HW);
}

__global__ __launch_bounds__(256) void scale_kernel(const float* __restrict__ x,
                                                    const float* __restrict__ pooled,
                                                    const float* __restrict__ w1,
                                                    const float* __restrict__ w2,
                                                    float* __restrict__ out,
                                                    int bc0) {
    const int bc = bc0 + blockIdx.x;
    const int b = bc >> 8, c0 = bc & 255;
    const int t = threadIdx.x;

    const vf4* xp = reinterpret_cast<const vf4*>(x + (size_t)bc * HW);
    vf4 v0 = xp[t];
    vf4 v1 = xp[t + 256];
    vf4 v2 = xp[t + 512];
    vf4 v3 = xp[t + 768];

    __shared__ float pl[C];
    __shared__ float yv[HID];
    __shared__ float red[4];
    __shared__ float sc_sh;

    pl[t] = pooled[b * C + t];
    __syncthreads();
    {
        const int h = t >> 4, j = t & 15;
        const float* w1r = w1 + h * C + j * 16;
        const float* plr = pl + j * 16;
        float p = 0.f;
#pragma unroll
        for (int k = 0; k < 16; ++k) p += plr[k] * w1r[k];
        p += __shfl_xor(p, 1, 64);
        p += __shfl_xor(p, 2, 64);
        p += __shfl_xor(p, 4, 64);
        p += __shfl_xor(p, 8, 64);
        if (j == 0) yv[h] = fmaxf(p, 0.f);
    }
    __syncthreads();
    float term = yv[t >> 4] * yv[t & 15] * w2[(size_t)c0 * BD + t];
#pragma unroll
    for (int off = 32; off > 0; off >>= 1) term += __shfl_down(term, off, 64);
    if ((t & 63) == 0) red[t >> 6] = term;
    __syncthreads();
    if (t == 0)
        sc_sh = 1.0f / (1.0f + expf(-((red[0] + red[1]) + (red[2] + red[3]))));
    __syncthreads();
    const float sc = sc_sh;

    vf4* op = reinterpret_cast<vf4*>(out + (size_t)bc * HW);
    v0 *= sc; v1 *= sc; v2 *= sc; v3 *= sc;
    __builtin_nontemporal_store(v0, &op[t]);
    __builtin_nontemporal_store(v1, &op[t + 256]);
    __builtin_nontemporal_store(v2, &op[t + 512]);
    __builtin_nontemporal_store(v3, &op[t + 768]);
}

extern "C" void kernel_launch(void* const* d_in, const int* in_sizes, int n_in,
                              void* d_out, int out_size, void* d_ws, size_t ws_size,
                              hipStream_t stream) {
    const float* x  = (const float*)d_in[0];
    const float* w1 = (const float*)d_in[1];
    const float* w2 = (const float*)d_in[2];
    float* out = (float*)d_out;

    float* pooled = (float*)d_ws;                                  // 32 KB (8192 f)
    unsigned int* bar = (unsigned int*)((char*)d_ws + (1 << 20));  // at +1 MB

    init_kernel<<<1, 64, 0, stream>>>(bar);
    void* args[] = {(void*)&x, (void*)&w1, (void*)&w2, (void*)&out,
                    (void*)&pooled, (void*)&bar};
    hipError_t err = hipLaunchCooperativeKernel((const void*)se_onebar, dim3(NBLK),
                                                dim3(TPB), args, 0, stream);
    if (err != hipSuccess) {
        for (int cb = 0; cb < B; cb += CHUNKB) {
            const int bc0 = cb * C;
            pool_kernel<<<CHUNKB * C, 256, 0, stream>>>(x, pooled, bc0);
            scale_kernel<<<CHUNKB * C, 256, 0, stream>>>(x, pooled, w1, w2, out, bc0);
        }
    }
}